// Round 9
// baseline (239.687 us; speedup 1.0000x reference)
//
#include <hip/hip_runtime.h>

// Problem constants
#define D 32
#define K 8
#define NPAIR 36

// ws layout (float offsets)
#define AFROFF 0        // A-fragments bf16 hi/lo (16x16x32): 8k x 4KB = 32 KB
#define C2OFF 8192      // (c'_t - cmax) * log2(e), 36
#define CMAXOFF 8228
#define TICKOFF 8232    // last-block ticket (unsigned), zeroed by setup2
#define LCOFF 8240      // Lc (cholesky factors), 8 x 32 x 32
#define PARTOFF 16448   // per-block partial sums (<=2048)

typedef short s16x8 __attribute__((ext_vector_type(8)));   // 8 bf16 (4 VGPR)
typedef float f32x4 __attribute__((ext_vector_type(4)));   // MFMA 16x16 acc

union FragU { uint4 u4; s16x8 s8; };

__host__ __device__ constexpr int gidx(int i, int j) {  // i<=j packed pair index
    return i * 8 + j - i * (i + 1) / 2;
}

// f32 -> bf16 (RNE) and back, via bit ops -- HW-proven in R6's v12 run.
static __device__ inline unsigned short f2bf(float v) {
    union { float f; unsigned u; } c; c.f = v;
    unsigned r = (c.u + 0x7FFFu + ((c.u >> 16) & 1u)) >> 16;
    return (unsigned short)r;
}
static __device__ inline float bf2f(unsigned short h) {
    union { unsigned u; float f; } c; c.u = ((unsigned)h) << 16;
    return c.f;
}

// pack 8 floats (v[0..7]) into hi/lo bf16x8 (as uint4 bit patterns) -- RNE,
// verbatim from the R6 HW-passed v12 kernel (no __builtin_amdgcn_perm).
static __device__ inline void pack8(const float* v, uint4& hi, uint4& lo) {
    unsigned hw[4], lw[4];
    #pragma unroll
    for (int p = 0; p < 4; ++p) {
        const unsigned short h0 = f2bf(v[2 * p]);
        const unsigned short h1 = f2bf(v[2 * p + 1]);
        hw[p] = (unsigned)h0 | ((unsigned)h1 << 16);
        lw[p] = (unsigned)f2bf(v[2 * p] - bf2f(h0))
              | ((unsigned)f2bf(v[2 * p + 1] - bf2f(h1)) << 16);
    }
    hi = make_uint4(hw[0], hw[1], hw[2], hw[3]);
    lo = make_uint4(lw[0], lw[1], lw[2], lw[3]);
}

// ---------------------------------------------------------------------------
// setup1: per-cluster block. A = L L^T + I, Cholesky Lc, invLc. Emits invLc
// as bf16 hi/lo A-FRAGMENTS for mfma_f32_16x16x32_bf16: frag(k, rb, hl),
// lane t holds row = rb*16 + (t&15), k-elem = (t>>4)*8 + e. No w needed:
// main folds mu into the B operand (y = invLc (x - mu)).
// ---------------------------------------------------------------------------
__global__ __launch_bounds__(64) void setup1_kernel(
    const float* __restrict__ mu, const float* __restrict__ L,
    float* __restrict__ ws)
{
    __shared__ float sA[D][D + 1];
    __shared__ float sLc[D][D + 1];
    __shared__ float sI[D][D + 1];
    const int k = blockIdx.x;
    const int tid = threadIdx.x;
    const int i = tid & 31;

    for (int e = tid; e < D * D; e += 64) sI[e >> 5][e & 31] = L[k * D * D + e];
    __syncthreads();

    for (int e = tid; e < D * D; e += 64) {
        const int a = e >> 5, c = e & 31;
        float s = (a == c) ? 1.0f : 0.0f;
        #pragma unroll
        for (int b = 0; b < D; ++b) s = fmaf(sI[a][b], sI[c][b], s);
        sA[a][c] = s;
    }
    __syncthreads();

    float lrow[D];
    #pragma unroll
    for (int j = 0; j < D; ++j) {
        if (i == j) {
            float s = sA[j][j];
            #pragma unroll
            for (int b = 0; b < j; ++b) s = fmaf(-lrow[b], lrow[b], s);
            const float d = sqrtf(s);
            lrow[j] = d;
            #pragma unroll
            for (int b = 0; b < j; ++b) sLc[j][b] = lrow[b];
            sLc[j][j] = d;
        }
        __syncthreads();
        if (i > j) {
            float s = sA[i][j];
            #pragma unroll
            for (int b = 0; b < j; ++b) s = fmaf(-lrow[b], sLc[j][b], s);
            lrow[j] = s / sLc[j][j];
        }
    }
    __syncthreads();

    for (int e = tid; e < D * D; e += 64) {
        const int r = e >> 5, c = e & 31;
        ws[LCOFF + k * D * D + e] = (c <= r) ? sLc[r][c] : 0.0f;
    }

    {   // invLc column j
        const int j = i;
        #pragma unroll
        for (int ii = 0; ii < D; ++ii) {
            float s = (ii == j) ? 1.0f : 0.0f;
            #pragma unroll
            for (int b = 0; b < ii; ++b) s = fmaf(-sLc[ii][b], sI[b][j], s);
            sI[ii][j] = s / sLc[ii][ii];
        }
    }
    __syncthreads();   // sI now full invLc

    // A-fragments for 16x16x32: row = rb*16 + (t&15), k-elem = (t>>4)*8 + e
    #pragma unroll
    for (int rb = 0; rb < 2; ++rb) {
        float v[8];
        #pragma unroll
        for (int e = 0; e < 8; ++e)
            v[e] = sI[rb * 16 + (tid & 15)][(tid >> 4) * 8 + e];
        uint4 hi, lo;
        pack8(v, hi, lo);
        char* base = (char*)ws + k * 4096;
        *(uint4*)(base + (rb * 2 + 0) * 1024 + tid * 16) = hi;
        *(uint4*)(base + (rb * 2 + 1) * 1024 + tid * 16) = lo;
    }
}

// ---------------------------------------------------------------------------
// setup2 (proven): pair constants c2, cmax; zeroes the finish ticket.
// ---------------------------------------------------------------------------
#define SLC(kk, r, c) sLc2[(kk) * 1024 + (r) * 32 + (c)]

__global__ __launch_bounds__(256) void setup2_kernel(
    const float* __restrict__ mu, const float* __restrict__ weights,
    float* __restrict__ ws)
{
    __shared__ float sLc2[K * D * D];   // 32 KB
    __shared__ float sMu[K * D];
    __shared__ float sWt[K];
    __shared__ float sLogw[K];
    __shared__ float sCp[NPAIR];
    __shared__ float sCmax;
    const int tid = threadIdx.x;

    {
        const float4* src = (const float4*)(ws + LCOFF);
        float4* dst = (float4*)sLc2;
        #pragma unroll
        for (int e = 0; e < 8; ++e) dst[tid + 256 * e] = src[tid + 256 * e];
        sMu[tid] = mu[tid];
        if (tid < K) sWt[tid] = weights[tid];
    }
    __syncthreads();

    if (tid == 0) {
        float m = -INFINITY;
        for (int t = 0; t < K; ++t) m = fmaxf(m, sWt[t]);
        float s = 0.0f;
        for (int t = 0; t < K; ++t) s += expf(sWt[t] - m);
        const float lse = m + logf(s);
        for (int t = 0; t < K; ++t) sLogw[t] = sWt[t] - lse;
        *(unsigned int*)(ws + TICKOFF) = 0u;
    }
    __syncthreads();

    if (tid < NPAIR) {
        int tt = tid, pi = 0;
        while (tt >= (K - pi)) { tt -= (K - pi); ++pi; }
        const int pj = pi + tt;
        const float LOG2PI = 1.8378770664093453f;
        float sumlogS = 0.0f, logdetsig = 0.0f;
        #pragma unroll
        for (int r = 0; r < D; ++r) {
            const float di = SLC(pi, r, r), dj = SLC(pj, r, r);
            sumlogS += logf(di + dj);
            logdetsig -= logf(1.0f / di + 1.0f / dj);
        }
        float v[D];
        float quad_acc = 0.0f;
        #pragma unroll
        for (int r = 0; r < D; ++r) {
            const float d0 = sMu[pi * D + r] - sMu[pj * D + r];
            float s = d0;
            #pragma unroll
            for (int b = 0; b < r; ++b)
                s = fmaf(-(SLC(pi, r, b) + SLC(pj, r, b)), v[b], s);
            v[r] = s / (SLC(pi, r, r) + SLC(pj, r, r));
            quad_acc = fmaf(d0, v[r], quad_acc);
        }
        const float quad = -0.5f * quad_acc;
        float c = quad - 0.5f * sumlogS - (float)D * LOG2PI - 0.5f * logdetsig
                  + sLogw[pi] + sLogw[pj];
        if (pi < pj) c += 0.6931471805599453f;
        sCp[tid] = c;
    }
    __syncthreads();
    if (tid == 0) {
        float m = -INFINITY;
        for (int t = 0; t < NPAIR; ++t) m = fmaxf(m, sCp[t]);
        sCmax = m;
        ws[CMAXOFF] = m;
    }
    __syncthreads();
    if (tid < NPAIR)
        ws[C2OFF + tid] = (sCp[tid] - sCmax) * 1.4426950408889634f;
}

// ---------------------------------------------------------------------------
// main v13b (16x16x32 MFMA): 256 thr = 4 waves x 16 samples. Lane l: sample
// col = l&15; holds rows {4g..4g+3} + {16+4g..} where g = l>>4; its x k-slice
// is g*8..g*8+7. Per k: B = (x - mu_k) hi/lo (mu folded in: y = invLc(x-mu),
// no w array; robust to A/B permutation ambiguity). 6 MFMA per k, acc init 0.
// yk = 8 k x 8 f32 = 64 VGPR (half of v12); Gram on the fly (diag[8] then
// per-pair 8 fma -> q -> 2 shfl -> exp2 -> discard; no G[36] array). Target:
// VGPR <= 128 -> 4 waves/SIMD -> latency finally hidden.
// ---------------------------------------------------------------------------
__global__ __launch_bounds__(256) void main_kernel(
    const float* __restrict__ X, const float* __restrict__ mu,
    const float* __restrict__ cst,
    float* __restrict__ partials, float* __restrict__ out,
    unsigned int* __restrict__ ticket, int nsamp, int nblk)
{
    __shared__ float sRed[4];
    __shared__ int sIsLast;
    const int tid = threadIdx.x;
    const int wv = tid >> 6;
    const int lane = tid & 63;
    const int col = lane & 15;         // sample within wave
    const int g = lane >> 4;           // k-slice / row-quad selector

    const int n = blockIdx.x * 64 + wv * 16 + col;
    const int m = (n < nsamp) ? n : 0;

    // x k-slice for this lane: x[m][g*8 .. g*8+7]
    float xr[8];
    {
        const float4 a0 = *(const float4*)(X + m * D + g * 8);
        const float4 a1 = *(const float4*)(X + m * D + g * 8 + 4);
        xr[0] = a0.x; xr[1] = a0.y; xr[2] = a0.z; xr[3] = a0.w;
        xr[4] = a1.x; xr[5] = a1.y; xr[6] = a1.z; xr[7] = a1.w;
    }

    const char* afr = (const char*)cst;            // AFROFF == 0

    f32x4 yk0[K], yk1[K];   // row-blocks 0/1: 64 VGPR total
    #pragma unroll
    for (int k = 0; k < K; ++k) {
        // B = x - mu_k (lane's 8-elem k-slice), packed hi/lo
        float b[8];
        {
            const float4 m40 = *(const float4*)(mu + k * D + g * 8);
            const float4 m41 = *(const float4*)(mu + k * D + g * 8 + 4);
            b[0] = xr[0] - m40.x; b[1] = xr[1] - m40.y;
            b[2] = xr[2] - m40.z; b[3] = xr[3] - m40.w;
            b[4] = xr[4] - m41.x; b[5] = xr[5] - m41.y;
            b[6] = xr[6] - m41.z; b[7] = xr[7] - m41.w;
        }
        FragU bh, bl;
        pack8(b, bh.u4, bl.u4);

        FragU ah0, al0, ah1, al1;
        const char* base = afr + k * 4096 + lane * 16;
        ah0.u4 = *(const uint4*)(base);
        al0.u4 = *(const uint4*)(base + 1024);
        ah1.u4 = *(const uint4*)(base + 2048);
        al1.u4 = *(const uint4*)(base + 3072);

        f32x4 p0 = (f32x4)(0.0f), q0 = (f32x4)(0.0f);
        f32x4 p1 = (f32x4)(0.0f), q1 = (f32x4)(0.0f);
        p0 = __builtin_amdgcn_mfma_f32_16x16x32_bf16(ah0.s8, bh.s8, p0, 0, 0, 0);
        q0 = __builtin_amdgcn_mfma_f32_16x16x32_bf16(al0.s8, bh.s8, q0, 0, 0, 0);
        p1 = __builtin_amdgcn_mfma_f32_16x16x32_bf16(ah1.s8, bh.s8, p1, 0, 0, 0);
        q1 = __builtin_amdgcn_mfma_f32_16x16x32_bf16(al1.s8, bh.s8, q1, 0, 0, 0);
        q0 = __builtin_amdgcn_mfma_f32_16x16x32_bf16(ah0.s8, bl.s8, q0, 0, 0, 0);
        q1 = __builtin_amdgcn_mfma_f32_16x16x32_bf16(ah1.s8, bl.s8, q1, 0, 0, 0);
        yk0[k] = p0 + q0;
        yk1[k] = p1 + q1;
    }

    // Gram diagonals (lane's 8 rows of its sample)
    float dg[K];
    #pragma unroll
    for (int k = 0; k < K; ++k) {
        float s = 0.0f;
        #pragma unroll
        for (int r = 0; r < 4; ++r) {
            s = fmaf(yk0[k][r], yk0[k][r], s);
            s = fmaf(yk1[k][r], yk1[k][r], s);
        }
        dg[k] = s;
    }

    // pairs on the fly: p -> q -> combine 4-lane quartet -> exp2 -> accumulate
    float accs = 0.0f;
    const float NH = -0.72134752044448170f;   // -0.5*log2(e)
    #pragma unroll
    for (int pi = 0; pi < K; ++pi)
        #pragma unroll
        for (int pj = pi; pj < K; ++pj) {
            float p = 0.0f;
            #pragma unroll
            for (int r = 0; r < 4; ++r) {
                p = fmaf(yk0[pi][r], yk0[pj][r], p);
                p = fmaf(yk1[pi][r], yk1[pj][r], p);
            }
            const float q = 2.0f * p + dg[pi] + dg[pj];
            const float t = q + __shfl_xor(q, 16, 64);
            const float qf = t + __shfl_xor(t, 32, 64);   // full 32-row sum
            accs += exp2f(fmaf(NH, qf, cst[C2OFF + gidx(pi, pj)]));
        }
    accs = (n < nsamp) ? accs : 0.0f;

    // wave reduce (each sample 4x duplicated across its lane quartet -> x0.25)
    #pragma unroll
    for (int s = 1; s < 64; s <<= 1) accs += __shfl_xor(accs, s, 64);
    if (lane == 0) sRed[wv] = 0.25f * accs;
    __syncthreads();

    if (tid == 0) {
        const float blocksum = sRed[0] + sRed[1] + sRed[2] + sRed[3];
        partials[blockIdx.x] = blocksum;
        __threadfence();                              // release partial
        const unsigned prev = atomicAdd(ticket, 1u);  // device scope (G12)
        sIsLast = (prev == (unsigned)(nblk - 1)) ? 1 : 0;
    }
    __syncthreads();

    if (sIsLast) {                                    // folded finish kernel
        __threadfence();                              // acquire partials
        float a2 = 0.0f;
        for (int e = tid; e < nblk; e += 256) a2 += partials[e];
        #pragma unroll
        for (int s = 1; s < 64; s <<= 1) a2 += __shfl_xor(a2, s, 64);
        if ((tid & 63) == 0) sRed[tid >> 6] = a2;
        __syncthreads();
        if (tid == 0)
            out[0] = cst[CMAXOFF]
                   + logf(sRed[0] + sRed[1] + sRed[2] + sRed[3]);
    }
}

extern "C" void kernel_launch(void* const* d_in, const int* in_sizes, int n_in,
                              void* d_out, int out_size, void* d_ws, size_t ws_size,
                              hipStream_t stream) {
    const float* X = (const float*)d_in[0];
    const float* mu = (const float*)d_in[1];
    const float* L = (const float*)d_in[2];
    const float* w = (const float*)d_in[3];
    float* wsf = (float*)d_ws;
    float* out = (float*)d_out;

    const int nsamp = in_sizes[0] / D;
    const int nblk = (nsamp + 63) / 64;   // 64 samples per 4-wave block

    setup1_kernel<<<K, 64, 0, stream>>>(mu, L, wsf);
    setup2_kernel<<<1, 256, 0, stream>>>(mu, w, wsf);
    main_kernel<<<nblk, 256, 0, stream>>>(X, mu, wsf, wsf + PARTOFF, out,
                                          (unsigned int*)(wsf + TICKOFF),
                                          nsamp, nblk);
}

// Round 10
// 141.413 us; speedup vs baseline: 1.6949x; 1.6949x over previous
//
#include <hip/hip_runtime.h>

// Problem constants
#define D 32
#define K 8
#define NPAIR 36

// ws layout (float offsets) -- identical to the R6 HW-passed v12 kernel
#define AFROFF 0        // A-fragments bf16 hi/lo: 8k x 4KB = 32 KB (8192 floats)
#define WFROFF 8192     // -w in C-frag order: [k][half][16] = 256 floats
#define C2OFF 8448      // (c'_t - cmax) * log2(e), 36
#define CMAXOFF 8484
#define TICKOFF 8488    // last-block ticket (unsigned), zeroed by setup2
#define LCOFF 8512      // Lc (cholesky factors), 8 x 32 x 32
#define PARTOFF 16704   // per-block partial sums (<=1024)

typedef short s16x8 __attribute__((ext_vector_type(8)));    // 8 bf16 (4 VGPR)
typedef float f32x16 __attribute__((ext_vector_type(16)));  // MFMA 32x32 acc

union FragU { uint4 u4; s16x8 s8; };

__host__ __device__ constexpr int gidx(int i, int j) {  // i<=j packed pair index
    return i * 8 + j - i * (i + 1) / 2;
}

// f32 -> bf16 (RNE) and back, via bit ops -- HW-proven (R6 v12 run)
static __device__ inline unsigned short f2bf(float v) {
    union { float f; unsigned u; } c; c.f = v;
    unsigned r = (c.u + 0x7FFFu + ((c.u >> 16) & 1u)) >> 16;
    return (unsigned short)r;
}
static __device__ inline float bf2f(unsigned short h) {
    union { unsigned u; float f; } c; c.u = ((unsigned)h) << 16;
    return c.f;
}

// pack 8 floats (v[0..7]) into hi/lo bf16x8 (as uint4 bit patterns) -- RNE
static __device__ inline void pack8(const float* v, uint4& hi, uint4& lo) {
    unsigned hw[4], lw[4];
    #pragma unroll
    for (int p = 0; p < 4; ++p) {
        const unsigned short h0 = f2bf(v[2 * p]);
        const unsigned short h1 = f2bf(v[2 * p + 1]);
        hw[p] = (unsigned)h0 | ((unsigned)h1 << 16);
        lw[p] = (unsigned)f2bf(v[2 * p] - bf2f(h0))
              | ((unsigned)f2bf(v[2 * p + 1] - bf2f(h1)) << 16);
    }
    hi = make_uint4(hw[0], hw[1], hw[2], hw[3]);
    lo = make_uint4(lw[0], lw[1], lw[2], lw[3]);
}

// ---------------------------------------------------------------------------
// setup1 (R6 v12 VERBATIM, HW-passed): A = L L^T + I, Cholesky, invLc; emits
// invLc as bf16 hi/lo A-fragments (32x32x16 layout: lane t row=t&31,
// c=16s+8*(t>>5)+e) and -w in MFMA C-layout order.
// ---------------------------------------------------------------------------
__global__ __launch_bounds__(64) void setup1_kernel(
    const float* __restrict__ mu, const float* __restrict__ L,
    float* __restrict__ ws)
{
    __shared__ float sA[D][D + 1];
    __shared__ float sLc[D][D + 1];
    __shared__ float sI[D][D + 1];
    __shared__ float sWv[D];
    const int k = blockIdx.x;
    const int tid = threadIdx.x;
    const int i = tid & 31;
    const int row = tid & 31;
    const int hg = tid >> 5;

    for (int e = tid; e < D * D; e += 64) sI[e >> 5][e & 31] = L[k * D * D + e];
    __syncthreads();

    for (int e = tid; e < D * D; e += 64) {
        const int a = e >> 5, c = e & 31;
        float s = (a == c) ? 1.0f : 0.0f;
        #pragma unroll
        for (int b = 0; b < D; ++b) s = fmaf(sI[a][b], sI[c][b], s);
        sA[a][c] = s;
    }
    __syncthreads();

    float lrow[D];
    #pragma unroll
    for (int j = 0; j < D; ++j) {
        if (i == j) {
            float s = sA[j][j];
            #pragma unroll
            for (int b = 0; b < j; ++b) s = fmaf(-lrow[b], lrow[b], s);
            const float d = sqrtf(s);
            lrow[j] = d;
            #pragma unroll
            for (int b = 0; b < j; ++b) sLc[j][b] = lrow[b];
            sLc[j][j] = d;
        }
        __syncthreads();
        if (i > j) {
            float s = sA[i][j];
            #pragma unroll
            for (int b = 0; b < j; ++b) s = fmaf(-lrow[b], sLc[j][b], s);
            lrow[j] = s / sLc[j][j];
        }
    }
    __syncthreads();

    for (int e = tid; e < D * D; e += 64) {
        const int r = e >> 5, c = e & 31;
        ws[LCOFF + k * D * D + e] = (c <= r) ? sLc[r][c] : 0.0f;
    }

    {   // invLc column j
        const int j = i;
        #pragma unroll
        for (int ii = 0; ii < D; ++ii) {
            float s = (ii == j) ? 1.0f : 0.0f;
            #pragma unroll
            for (int b = 0; b < ii; ++b) s = fmaf(-sLc[ii][b], sI[b][j], s);
            sI[ii][j] = s / sLc[ii][ii];
        }
    }
    __syncthreads();   // sI now full invLc

    // w_k[i] = sum_b invLc[i][b] mu[b]
    {
        float s = 0.0f;
        #pragma unroll
        for (int b = 0; b < D; ++b) s = fmaf(sI[i][b], mu[k * D + b], s);
        if (tid < 32) sWv[i] = s;
    }

    // A-fragments: frag(k, s, hl) lane t holds row=t&31, c=16s+8*(t>>5)+e
    #pragma unroll
    for (int s = 0; s < 2; ++s) {
        float v[8];
        #pragma unroll
        for (int e = 0; e < 8; ++e) v[e] = sI[row][16 * s + 8 * hg + e];
        uint4 hi, lo;
        pack8(v, hi, lo);
        *(uint4*)((char*)ws + AFROFF * 4 + k * 4096 + ((s * 2 + 0) * 64 + tid) * 16) = hi;
        *(uint4*)((char*)ws + AFROFF * 4 + k * 4096 + ((s * 2 + 1) * 64 + tid) * 16) = lo;
    }
    __syncthreads();

    // -w in MFMA C-layout order: [k][half h][reg r] = -w[(r&3)+8*(r>>2)+4h]
    if (tid < 32) {
        const int h = tid >> 4, r = tid & 15;
        ws[WFROFF + k * 32 + h * 16 + r] = -sWv[(r & 3) + 8 * (r >> 2) + 4 * h];
    }
}

// ---------------------------------------------------------------------------
// setup2 (R6 v12 VERBATIM): pair constants c2, cmax; zeroes the finish ticket.
// ---------------------------------------------------------------------------
#define SLC(kk, r, c) sLc2[(kk) * 1024 + (r) * 32 + (c)]

__global__ __launch_bounds__(256) void setup2_kernel(
    const float* __restrict__ mu, const float* __restrict__ weights,
    float* __restrict__ ws)
{
    __shared__ float sLc2[K * D * D];   // 32 KB
    __shared__ float sMu[K * D];
    __shared__ float sWt[K];
    __shared__ float sLogw[K];
    __shared__ float sCp[NPAIR];
    __shared__ float sCmax;
    const int tid = threadIdx.x;

    {
        const float4* src = (const float4*)(ws + LCOFF);
        float4* dst = (float4*)sLc2;
        #pragma unroll
        for (int e = 0; e < 8; ++e) dst[tid + 256 * e] = src[tid + 256 * e];
        sMu[tid] = mu[tid];
        if (tid < K) sWt[tid] = weights[tid];
    }
    __syncthreads();

    if (tid == 0) {
        float m = -INFINITY;
        for (int t = 0; t < K; ++t) m = fmaxf(m, sWt[t]);
        float s = 0.0f;
        for (int t = 0; t < K; ++t) s += expf(sWt[t] - m);
        const float lse = m + logf(s);
        for (int t = 0; t < K; ++t) sLogw[t] = sWt[t] - lse;
        *(unsigned int*)(ws + TICKOFF) = 0u;
    }
    __syncthreads();

    if (tid < NPAIR) {
        int tt = tid, pi = 0;
        while (tt >= (K - pi)) { tt -= (K - pi); ++pi; }
        const int pj = pi + tt;
        const float LOG2PI = 1.8378770664093453f;
        float sumlogS = 0.0f, logdetsig = 0.0f;
        #pragma unroll
        for (int r = 0; r < D; ++r) {
            const float di = SLC(pi, r, r), dj = SLC(pj, r, r);
            sumlogS += logf(di + dj);
            logdetsig -= logf(1.0f / di + 1.0f / dj);
        }
        float v[D];
        float quad_acc = 0.0f;
        #pragma unroll
        for (int r = 0; r < D; ++r) {
            const float d0 = sMu[pi * D + r] - sMu[pj * D + r];
            float s = d0;
            #pragma unroll
            for (int b = 0; b < r; ++b)
                s = fmaf(-(SLC(pi, r, b) + SLC(pj, r, b)), v[b], s);
            v[r] = s / (SLC(pi, r, r) + SLC(pj, r, r));
            quad_acc = fmaf(d0, v[r], quad_acc);
        }
        const float quad = -0.5f * quad_acc;
        float c = quad - 0.5f * sumlogS - (float)D * LOG2PI - 0.5f * logdetsig
                  + sLogw[pi] + sLogw[pj];
        if (pi < pj) c += 0.6931471805599453f;
        sCp[tid] = c;
    }
    __syncthreads();
    if (tid == 0) {
        float m = -INFINITY;
        for (int t = 0; t < NPAIR; ++t) m = fmaxf(m, sCp[t]);
        sCmax = m;
        ws[CMAXOFF] = m;
    }
    __syncthreads();
    if (tid < NPAIR)
        ws[C2OFF + tid] = (sCp[tid] - sCmax) * 1.4426950408889634f;
}

// ---------------------------------------------------------------------------
// main v14: v12's HW-passed structure (4 waves x 32 distinct samples, 32x32x16
// MFMA, -w acc init, Gram-on-accumulators epilogue) + two latency fixes:
//   (1) A/w-frag table (33 KB) staged into LDS once per block; per-k operand
//       reads become per-lane ds_read_b128 (full 1KB/instr -- NOT broadcast).
//   (2) explicit 1-deep k-pipeline: prefetch k+1 frags into fA[(k+1)&1]
//       (static index under full unroll) while k's 6 MFMAs run.
// ---------------------------------------------------------------------------
__global__ __launch_bounds__(256) void main_kernel(
    const float* __restrict__ X, const float* __restrict__ cst,
    float* __restrict__ partials, float* __restrict__ out,
    unsigned int* __restrict__ ticket, int nsamp, int nblk)
{
    __shared__ __align__(16) float sAfr[8448];   // A-frags 32KB + w-frags 1KB
    __shared__ float sC2[NPAIR];
    __shared__ float sRed[4];
    __shared__ int sIsLast;
    const int tid = threadIdx.x;
    const int wv = tid >> 6;
    const int lane = tid & 63;
    const int col = lane & 31;         // sample within wave group
    const int hg = lane >> 5;          // k-half / row-half selector

    const int n = blockIdx.x * 128 + wv * 32 + col;
    const int m = (n < nsamp) ? n : 0;

    // B-fragments from x (lane's k-slices: 8hg..8hg+7 and 16+8hg..16+8hg+7)
    FragU bh0, bl0, bh1, bl1;
    {
        const float4 a0 = *(const float4*)(X + m * D + 8 * hg);
        const float4 a1 = *(const float4*)(X + m * D + 8 * hg + 4);
        const float4 a2 = *(const float4*)(X + m * D + 16 + 8 * hg);
        const float4 a3 = *(const float4*)(X + m * D + 16 + 8 * hg + 4);
        float v0[8] = {a0.x, a0.y, a0.z, a0.w, a1.x, a1.y, a1.z, a1.w};
        float v1[8] = {a2.x, a2.y, a2.z, a2.w, a3.x, a3.y, a3.z, a3.w};
        pack8(v0, bh0.u4, bl0.u4);
        pack8(v1, bh1.u4, bl1.u4);
    }

    {   // stage A-frags + w-frags (8448 floats = 2112 float4) + c2 into LDS
        const float4* src = (const float4*)cst;     // AFROFF==0, WFROFF contiguous
        float4* dst = (float4*)sAfr;
        for (int e = tid; e < 2112; e += 256) dst[e] = src[e];
        if (tid < NPAIR) sC2[tid] = cst[C2OFF + tid];
    }
    __syncthreads();

    const char* afr = (const char*)sAfr;
    const float* wfr = sAfr + 8192;

    f32x16 yk[K];
    FragU fA[2][4];                    // double-buffered A-frags (static idx)
    #pragma unroll
    for (int f = 0; f < 4; ++f)
        fA[0][f].u4 = *(const uint4*)(afr + (f * 64 + lane) * 16);   // k=0

    #pragma unroll
    for (int k = 0; k < K; ++k) {
        const int cb = k & 1;          // compile-time under full unroll
        if (k + 1 < K) {               // prefetch next k's fragments
            #pragma unroll
            for (int f = 0; f < 4; ++f)
                fA[cb ^ 1][f].u4 = *(const uint4*)(
                    afr + (k + 1) * 4096 + (f * 64 + lane) * 16);
        }

        f32x16 acc1;
        {
            const float4* wp = (const float4*)(wfr + k * 32 + hg * 16);
            const float4 w0 = wp[0], w1 = wp[1], w2 = wp[2], w3 = wp[3];
            acc1[0] = w0.x;  acc1[1] = w0.y;  acc1[2] = w0.z;  acc1[3] = w0.w;
            acc1[4] = w1.x;  acc1[5] = w1.y;  acc1[6] = w1.z;  acc1[7] = w1.w;
            acc1[8] = w2.x;  acc1[9] = w2.y;  acc1[10] = w2.z; acc1[11] = w2.w;
            acc1[12] = w3.x; acc1[13] = w3.y; acc1[14] = w3.z; acc1[15] = w3.w;
        }
        f32x16 acc2 = (f32x16)(0.0f);

        // 6-MFMA hi/lo order verbatim from v12 (ah0,al0,ah1,al1 = fA[cb][0..3])
        acc1 = __builtin_amdgcn_mfma_f32_32x32x16_bf16(fA[cb][0].s8, bh0.s8, acc1, 0, 0, 0);
        acc2 = __builtin_amdgcn_mfma_f32_32x32x16_bf16(fA[cb][3].s8, bh1.s8, acc2, 0, 0, 0);
        acc1 = __builtin_amdgcn_mfma_f32_32x32x16_bf16(fA[cb][2].s8, bh1.s8, acc1, 0, 0, 0);
        acc2 = __builtin_amdgcn_mfma_f32_32x32x16_bf16(fA[cb][0].s8, bl0.s8, acc2, 0, 0, 0);
        acc1 = __builtin_amdgcn_mfma_f32_32x32x16_bf16(fA[cb][1].s8, bh0.s8, acc1, 0, 0, 0);
        acc2 = __builtin_amdgcn_mfma_f32_32x32x16_bf16(fA[cb][2].s8, bl1.s8, acc2, 0, 0, 0);

        yk[k] = acc1 + acc2;
    }

    // Gram on accumulators: lane's 16 rows (other half of the 32 in lane^32)
    float G[NPAIR];
    #pragma unroll
    for (int pi = 0; pi < K; ++pi)
        #pragma unroll
        for (int pj = pi; pj < K; ++pj) {
            float g = 0.0f;
            #pragma unroll
            for (int r = 0; r < 16; ++r)
                g = fmaf(yk[pi][r], yk[pj][r], g);
            G[gidx(pi, pj)] = g;
        }

    float accs = 0.0f;
    const float NH = -0.72134752044448170f;   // -0.5*log2(e)
    #pragma unroll
    for (int pi = 0; pi < K; ++pi)
        #pragma unroll
        for (int pj = pi; pj < K; ++pj) {
            const float q = 2.0f * G[gidx(pi, pj)]
                          + G[gidx(pi, pi)] + G[gidx(pj, pj)];
            const float qf = q + __shfl_xor(q, 32, 64);   // combine row halves
            accs += exp2f(fmaf(NH, qf, sC2[gidx(pi, pj)]));
        }
    accs = (n < nsamp) ? accs : 0.0f;

    // wave reduce (each sample duplicated in lane pair -> x0.5)
    #pragma unroll
    for (int s = 1; s < 64; s <<= 1) accs += __shfl_xor(accs, s, 64);
    if (lane == 0) sRed[wv] = 0.5f * accs;
    __syncthreads();

    if (tid == 0) {
        const float blocksum = sRed[0] + sRed[1] + sRed[2] + sRed[3];
        partials[blockIdx.x] = blocksum;
        __threadfence();                              // release partial
        const unsigned prev = atomicAdd(ticket, 1u);  // device scope (G12)
        sIsLast = (prev == (unsigned)(nblk - 1)) ? 1 : 0;
    }
    __syncthreads();

    if (sIsLast) {                                    // folded finish kernel
        __threadfence();                              // acquire partials
        float a2 = 0.0f;
        for (int e = tid; e < nblk; e += 256) a2 += partials[e];
        #pragma unroll
        for (int s = 1; s < 64; s <<= 1) a2 += __shfl_xor(a2, s, 64);
        if ((tid & 63) == 0) sRed[tid >> 6] = a2;
        __syncthreads();
        if (tid == 0)
            out[0] = cst[CMAXOFF]
                   + logf(sRed[0] + sRed[1] + sRed[2] + sRed[3]);
    }
}

extern "C" void kernel_launch(void* const* d_in, const int* in_sizes, int n_in,
                              void* d_out, int out_size, void* d_ws, size_t ws_size,
                              hipStream_t stream) {
    const float* X = (const float*)d_in[0];
    const float* mu = (const float*)d_in[1];
    const float* L = (const float*)d_in[2];
    const float* w = (const float*)d_in[3];
    float* wsf = (float*)d_ws;
    float* out = (float*)d_out;

    const int nsamp = in_sizes[0] / D;
    const int nblk = (nsamp + 127) / 128;   // 128 samples per 4-wave block

    setup1_kernel<<<K, 64, 0, stream>>>(mu, L, wsf);
    setup2_kernel<<<1, 256, 0, stream>>>(mu, w, wsf);
    main_kernel<<<nblk, 256, 0, stream>>>(X, wsf, wsf + PARTOFF, out,
                                          (unsigned int*)(wsf + TICKOFF),
                                          nsamp, nblk);
}